// Round 2
// baseline (609.148 us; speedup 1.0000x reference)
//
#include <hip/hip_runtime.h>
#include <stdint.h>

typedef unsigned short u16;
typedef __attribute__((ext_vector_type(4))) float  fvec4;
typedef __attribute__((ext_vector_type(4))) float  f32x4;
typedef __attribute__((ext_vector_type(8))) short  s16x8;
typedef __attribute__((ext_vector_type(4))) u16    u16x4;

#define AS1 __attribute__((address_space(1)))
#define AS3 __attribute__((address_space(3)))
#define MEMFENCE() asm volatile("" ::: "memory")

#define B_TOK   8192
#define NFRAG   16
#define FSZ     256
#define INF     4096
#define OUTF    4096
#define COMP    512

__device__ __forceinline__ u16 f2bf(float f){
  union { float fv; unsigned int u; } v; v.fv = f;
  unsigned int u = v.u;
  u += 0x7fffu + ((u >> 16) & 1u);
  return (u16)(u >> 16);
}

__device__ __forceinline__ void async16(const void* g, void* l){
  __builtin_amdgcn_global_load_lds((const AS1 unsigned int*)g, (AS3 unsigned int*)l, 16, 0, 0);
}

// ---------------- elementwise f32 -> bf16 cast (same layout) ----------------
__global__ void cast_bf16(const float* __restrict__ in, u16* __restrict__ out, int nquads){
  for (int i = blockIdx.x * blockDim.x + threadIdx.x; i < nquads; i += gridDim.x * blockDim.x){
    fvec4 v = ((const fvec4*)in)[i];
    u16x4 o; o.x = f2bf(v.x); o.y = f2bf(v.y); o.z = f2bf(v.z); o.w = f2bf(v.w);
    ((u16x4*)out)[i] = o;
  }
}

// ------------- transpose-cast expert weights: [16][256][4096] f32 -> [16][4096][256] bf16 -------------
__global__ void transpose_cast_w(const float* __restrict__ W, u16* __restrict__ Wt){
  __shared__ u16 ldsT[64][72];            // [n][k], padded row stride 144B (16B aligned)
  const int e  = blockIdx.z;
  const int kt = blockIdx.y;              // 0..3   (k tiles of 64 over 256)
  const int nt = blockIdx.x;              // 0..63  (n tiles of 64 over 4096)
  const int t  = threadIdx.x;
  const float* Wb = W + (size_t)e * FSZ * OUTF;

  const int tr = t >> 4;                  // 0..15
  const int tc = t & 15;                  // float4 col within 64
  #pragma unroll
  for (int it = 0; it < 4; ++it){
    int k = it * 16 + tr;                 // local k 0..63
    fvec4 v = *(const fvec4*)(Wb + (size_t)(kt * 64 + k) * OUTF + nt * 64 + tc * 4);
    ldsT[tc*4 + 0][k] = f2bf(v.x);
    ldsT[tc*4 + 1][k] = f2bf(v.y);
    ldsT[tc*4 + 2][k] = f2bf(v.z);
    ldsT[tc*4 + 3][k] = f2bf(v.w);
  }
  __syncthreads();
  u16* Wtb = Wt + (size_t)e * OUTF * FSZ;
  const int nr = t >> 3;                  // 0..31
  const int nc = t & 7;                   // 16B chunk within 64 k
  #pragma unroll
  for (int it = 0; it < 2; ++it){
    int n = it * 32 + nr;
    s16x8 val = *(const s16x8*)&ldsT[n][nc * 8];
    *(s16x8*)(Wtb + (size_t)(nt * 64 + n) * FSZ + kt * 64 + nc * 8) = val;
  }
}

// ---------------- prep: selector + argmax + bucket scatter + masked/xsel bf16 ----------------
__global__ void prep_kernel(const float* __restrict__ x, const float* __restrict__ sw,
                            u16* __restrict__ masked, u16* __restrict__ xsel,
                            int* __restrict__ counts, int* __restrict__ tok_list){
  const int b = blockIdx.x;
  const int t = threadIdx.x;
  const int f   = t >> 4;                 // fragment id 0..15
  const int l16 = t & 15;
  const float* xr = x + (size_t)b * INF;

  fvec4 v[4];
  float part = 0.f;
  #pragma unroll
  for (int j = 0; j < 4; ++j){
    v[j] = ((const fvec4*)xr)[t * 4 + j];                       // elements t*16 + j*4
    fvec4 w = ((const fvec4*)(sw + f * FSZ))[l16 * 4 + j];
    part += v[j].x * w.x + v[j].y * w.y + v[j].z * w.z + v[j].w * w.w;
  }
  #pragma unroll
  for (int m = 1; m < 16; m <<= 1) part += __shfl_xor(part, m, 64);

  __shared__ float sc[NFRAG];
  __shared__ int   ssel;
  if (l16 == 0) sc[f] = part;
  __syncthreads();
  if (t == 0){
    float best = sc[0]; int bi = 0;
    #pragma unroll
    for (int i = 1; i < NFRAG; ++i){ if (sc[i] > best){ best = sc[i]; bi = i; } }
    ssel = bi;
    int pos = atomicAdd(&counts[bi], 1);
    tok_list[bi * B_TOK + pos] = b;
  }
  __syncthreads();
  const int sel = ssel;
  const bool insel = (f == sel);
  #pragma unroll
  for (int j = 0; j < 4; ++j){
    u16x4 o;
    o.x = insel ? (u16)0 : f2bf(v[j].x);
    o.y = insel ? (u16)0 : f2bf(v[j].y);
    o.z = insel ? (u16)0 : f2bf(v[j].z);
    o.w = insel ? (u16)0 : f2bf(v[j].w);
    ((u16x4*)(masked + (size_t)b * INF))[t * 4 + j] = o;
  }
  if (insel){
    #pragma unroll
    for (int j = 0; j < 4; ++j){
      u16x4 o;
      o.x = f2bf(v[j].x); o.y = f2bf(v[j].y); o.z = f2bf(v[j].z); o.w = f2bf(v[j].w);
      ((u16x4*)(xsel + (size_t)b * FSZ))[l16 * 4 + j] = o;
    }
  }
}

// ---------------- templated 128x128xBK64 bf16 MFMA GEMM, B in [N][K] layout ----------------
// EPI: 0 = write bf16, 1 = write f32, 2 = scatter-add f32 via rowtok
template<int EPI, bool GATHER>
__global__ __launch_bounds__(256, 2)
void gemm_bt(const u16* __restrict__ A, int lda,
             const u16* __restrict__ B, int ldb,
             void* __restrict__ Cout, int ldc,
             int M, int N, int K,
             const int* __restrict__ tok_list,
             const int* __restrict__ counts){
  __shared__ u16 Ab[2][128 * 64];
  __shared__ u16 Bb[2][128 * 64];
  __shared__ int rowtok[128];

  const int t    = threadIdx.x;
  const int wv   = t >> 6;
  const int lane = t & 63;
  const int cx   = blockIdx.x;
  const int e    = GATHER ? blockIdx.z : 0;
  const int Me   = GATHER ? counts[e] : M;
  const u16* Bbase = GATHER ? (B + (size_t)e * ((size_t)N * K)) : B;
  const int KT   = K >> 6;
  const int wr = wv >> 1, wc = wv & 1;
  const int l15 = lane & 15, lq = lane >> 4;
  const int rstep = GATHER ? (int)gridDim.y : 65536;

  for (int ry = blockIdx.y; ry * 128 < Me; ry += rstep){
    if (GATHER){
      if (t < 128){
        int r  = ry * 128 + t;
        int rc = (r < Me) ? r : (Me - 1);
        rowtok[t] = tok_list[e * B_TOK + rc];
      }
      __syncthreads();
    }

    auto stage = [&](int buf, int kt){
      const int k0 = kt << 6;
      #pragma unroll
      for (int it = 0; it < 4; ++it){
        int G = it * 256 + wv * 64 + lane;
        int row = G >> 3;
        int g = (G & 7) ^ (row & 7);
        size_t arow = GATHER ? (size_t)rowtok[row] : (size_t)(ry * 128 + row);
        async16(A + arow * (size_t)lda + k0 + g * 8, &Ab[buf][(it * 256 + wv * 64) * 8]);
      }
      #pragma unroll
      for (int it = 0; it < 4; ++it){
        int G = it * 256 + wv * 64 + lane;
        int row = G >> 3;
        int g = (G & 7) ^ (row & 7);
        async16(Bbase + (size_t)(cx * 128 + row) * ldb + k0 + g * 8, &Bb[buf][(it * 256 + wv * 64) * 8]);
      }
    };

    f32x4 acc[4][4];
    #pragma unroll
    for (int i = 0; i < 4; ++i)
      #pragma unroll
      for (int j = 0; j < 4; ++j){
        f32x4 z = {0.f, 0.f, 0.f, 0.f};
        acc[i][j] = z;
      }

    stage(0, 0);
    for (int kt = 0; kt < KT; ++kt){
      const int cur = kt & 1;
      if (kt + 1 < KT){
        stage(cur ^ 1, kt + 1);
        __builtin_amdgcn_sched_barrier(0);
        asm volatile("s_waitcnt vmcnt(8)" ::: "memory");
      } else {
        __builtin_amdgcn_sched_barrier(0);
        asm volatile("s_waitcnt vmcnt(0)" ::: "memory");
      }
      MEMFENCE(); __builtin_amdgcn_s_barrier(); MEMFENCE();

      #pragma unroll
      for (int kk = 0; kk < 2; ++kk){
        s16x8 af[4], bfr[4];
        #pragma unroll
        for (int i = 0; i < 4; ++i){
          int row = wr * 64 + i * 16 + l15;
          int sg  = (kk * 4 + lq) ^ (row & 7);
          af[i] = *(const s16x8*)&Ab[cur][row * 64 + sg * 8];
        }
        #pragma unroll
        for (int j = 0; j < 4; ++j){
          int row = wc * 64 + j * 16 + l15;
          int sg  = (kk * 4 + lq) ^ (row & 7);
          bfr[j] = *(const s16x8*)&Bb[cur][row * 64 + sg * 8];
        }
        #pragma unroll
        for (int i = 0; i < 4; ++i)
          #pragma unroll
          for (int j = 0; j < 4; ++j)
            acc[i][j] = __builtin_amdgcn_mfma_f32_16x16x32_bf16(af[i], bfr[j], acc[i][j], 0, 0, 0);
      }

      MEMFENCE(); __builtin_amdgcn_s_barrier(); MEMFENCE();
    }

    // epilogue — C/D layout: col = lane&15, row = (lane>>4)*4 + reg
    #pragma unroll
    for (int i = 0; i < 4; ++i){
      #pragma unroll
      for (int j = 0; j < 4; ++j){
        int rloc = wr * 64 + i * 16 + lq * 4;
        int col  = cx * 128 + wc * 64 + j * 16 + l15;
        #pragma unroll
        for (int r = 0; r < 4; ++r){
          int rit = rloc + r;
          if (EPI == 0){
            ((u16*)Cout)[(size_t)(ry * 128 + rit) * ldc + col] = f2bf(acc[i][j][r]);
          } else if (EPI == 1){
            ((float*)Cout)[(size_t)(ry * 128 + rit) * ldc + col] = acc[i][j][r];
          } else {
            int rr = ry * 128 + rit;
            if (rr < Me){
              float* p = (float*)Cout + (size_t)rowtok[rit] * ldc + col;
              *p += acc[i][j][r];
            }
          }
        }
      }
    }
    if (GATHER) __syncthreads();
  }
}

// ---------------- host launcher ----------------
extern "C" void kernel_launch(void* const* d_in, const int* in_sizes, int n_in,
                              void* d_out, int out_size, void* d_ws, size_t ws_size,
                              hipStream_t stream){
  const float* x  = (const float*)d_in[0];
  const float* sw = (const float*)d_in[1];
  const float* W  = (const float*)d_in[2];
  const float* C  = (const float*)d_in[3];
  const float* D  = (const float*)d_in[4];
  float* out = (float*)d_out;

  char* w = (char*)d_ws;
  size_t off = 0;
  auto alloc = [&](size_t bytes) -> void* {
    void* p = w + off;
    off += (bytes + 255) & ~(size_t)255;
    return p;
  };
  u16* masked = (u16*)alloc((size_t)B_TOK * INF * 2);     // 67 MB
  u16* xsel   = (u16*)alloc((size_t)B_TOK * FSZ * 2);     // 4 MB
  u16* comp   = (u16*)alloc((size_t)B_TOK * COMP * 2);    // 8.4 MB
  u16* Cb     = (u16*)alloc((size_t)COMP * INF * 2);      // 4.2 MB
  u16* Db     = (u16*)alloc((size_t)OUTF * COMP * 2);     // 4.2 MB
  u16* Wt     = (u16*)alloc((size_t)NFRAG * OUTF * FSZ * 2); // 33.6 MB
  int* counts = (int*)alloc(NFRAG * sizeof(int));
  int* toks   = (int*)alloc((size_t)NFRAG * B_TOK * sizeof(int));

  hipMemsetAsync(counts, 0, NFRAG * sizeof(int), stream);

  cast_bf16<<<2048, 256, 0, stream>>>(C, Cb, (COMP * INF) / 4);
  cast_bf16<<<2048, 256, 0, stream>>>(D, Db, (OUTF * COMP) / 4);
  transpose_cast_w<<<dim3(64, 4, 16), 256, 0, stream>>>(W, Wt);
  prep_kernel<<<B_TOK, 256, 0, stream>>>(x, sw, masked, xsel, counts, toks);

  // compressed = masked @ C^T   -> bf16 [8192, 512]
  gemm_bt<0, false><<<dim3(COMP / 128, B_TOK / 128), 256, 0, stream>>>(
      masked, INF, Cb, INF, comp, COMP, B_TOK, COMP, INF, nullptr, nullptr);

  // out = compressed @ D^T      -> f32 [8192, 4096]
  gemm_bt<1, false><<<dim3(OUTF / 128, B_TOK / 128), 256, 0, stream>>>(
      comp, COMP, Db, COMP, out, OUTF, B_TOK, OUTF, COMP, nullptr, nullptr);

  // out += grouped expert GEMM (token-gathered A, per-expert Wt)
  gemm_bt<2, true><<<dim3(OUTF / 128, 8, NFRAG), 256, 0, stream>>>(
      xsel, FSZ, Wt, FSZ, out, OUTF, B_TOK, OUTF, FSZ, toks, counts);
}

// Round 3
// 513.034 us; speedup vs baseline: 1.1873x; 1.1873x over previous
//
#include <hip/hip_runtime.h>
#include <stdint.h>

typedef unsigned short u16;
typedef __attribute__((ext_vector_type(4))) float  fvec4;
typedef __attribute__((ext_vector_type(4))) float  f32x4;
typedef __attribute__((ext_vector_type(8))) short  s16x8;
typedef __attribute__((ext_vector_type(4))) u16    u16x4;

#define AS1 __attribute__((address_space(1)))
#define AS3 __attribute__((address_space(3)))
#define MEMFENCE() asm volatile("" ::: "memory")

#define B_TOK   8192
#define NFRAG   16
#define FSZ     256
#define INF     4096
#define OUTF    4096
#define COMP    512
#define KCAT    768      // COMP + FSZ

__device__ __forceinline__ u16 f2bf(float f){
  union { float fv; unsigned int u; } v; v.fv = f;
  unsigned int u = v.u;
  u += 0x7fffu + ((u >> 16) & 1u);
  return (u16)(u >> 16);
}

__device__ __forceinline__ void async16(const void* g, void* l){
  __builtin_amdgcn_global_load_lds((const AS1 unsigned int*)g, (AS3 unsigned int*)l, 16, 0, 0);
}

// ---------------- elementwise f32 -> bf16 cast (same layout) ----------------
__global__ void cast_bf16(const float* __restrict__ in, u16* __restrict__ out, int nquads){
  for (int i = blockIdx.x * blockDim.x + threadIdx.x; i < nquads; i += gridDim.x * blockDim.x){
    fvec4 v = ((const fvec4*)in)[i];
    u16x4 o; o.x = f2bf(v.x); o.y = f2bf(v.y); o.z = f2bf(v.z); o.w = f2bf(v.w);
    ((u16x4*)out)[i] = o;
  }
}

// ------------- transpose-cast expert weights: [16][256][4096] f32 -> [16][4096][256] bf16 -------------
__global__ void transpose_cast_w(const float* __restrict__ W, u16* __restrict__ Wt){
  __shared__ u16 ldsT[64][72];
  const int e  = blockIdx.z;
  const int kt = blockIdx.y;
  const int nt = blockIdx.x;
  const int t  = threadIdx.x;
  const float* Wb = W + (size_t)e * FSZ * OUTF;

  const int tr = t >> 4;
  const int tc = t & 15;
  #pragma unroll
  for (int it = 0; it < 4; ++it){
    int k = it * 16 + tr;
    fvec4 v = *(const fvec4*)(Wb + (size_t)(kt * 64 + k) * OUTF + nt * 64 + tc * 4);
    ldsT[tc*4 + 0][k] = f2bf(v.x);
    ldsT[tc*4 + 1][k] = f2bf(v.y);
    ldsT[tc*4 + 2][k] = f2bf(v.z);
    ldsT[tc*4 + 3][k] = f2bf(v.w);
  }
  __syncthreads();
  u16* Wtb = Wt + (size_t)e * OUTF * FSZ;
  const int nr = t >> 3;
  const int nc = t & 7;
  #pragma unroll
  for (int it = 0; it < 2; ++it){
    int n = it * 32 + nr;
    s16x8 val = *(const s16x8*)&ldsT[n][nc * 8];
    *(s16x8*)(Wtb + (size_t)(nt * 64 + n) * FSZ + kt * 64 + nc * 8) = val;
  }
}

// ---------------- prep: selector + argmax + bucket scatter + masked/xsel bf16 ----------------
// xsel is written into Acat columns [512,768) with row stride KCAT
__global__ void prep_kernel(const float* __restrict__ x, const float* __restrict__ sw,
                            u16* __restrict__ masked, u16* __restrict__ Acat,
                            int* __restrict__ counts, int* __restrict__ tok_list){
  const int b = blockIdx.x;
  const int t = threadIdx.x;
  const int f   = t >> 4;
  const int l16 = t & 15;
  const float* xr = x + (size_t)b * INF;

  fvec4 v[4];
  float part = 0.f;
  #pragma unroll
  for (int j = 0; j < 4; ++j){
    v[j] = ((const fvec4*)xr)[t * 4 + j];
    fvec4 w = ((const fvec4*)(sw + f * FSZ))[l16 * 4 + j];
    part += v[j].x * w.x + v[j].y * w.y + v[j].z * w.z + v[j].w * w.w;
  }
  #pragma unroll
  for (int m = 1; m < 16; m <<= 1) part += __shfl_xor(part, m, 64);

  __shared__ float sc[NFRAG];
  __shared__ int   ssel;
  if (l16 == 0) sc[f] = part;
  __syncthreads();
  if (t == 0){
    float best = sc[0]; int bi = 0;
    #pragma unroll
    for (int i = 1; i < NFRAG; ++i){ if (sc[i] > best){ best = sc[i]; bi = i; } }
    ssel = bi;
    int pos = atomicAdd(&counts[bi], 1);
    tok_list[bi * B_TOK + pos] = b;
  }
  __syncthreads();
  const int sel = ssel;
  const bool insel = (f == sel);
  #pragma unroll
  for (int j = 0; j < 4; ++j){
    u16x4 o;
    o.x = insel ? (u16)0 : f2bf(v[j].x);
    o.y = insel ? (u16)0 : f2bf(v[j].y);
    o.z = insel ? (u16)0 : f2bf(v[j].z);
    o.w = insel ? (u16)0 : f2bf(v[j].w);
    ((u16x4*)(masked + (size_t)b * INF))[t * 4 + j] = o;
  }
  if (insel){
    #pragma unroll
    for (int j = 0; j < 4; ++j){
      u16x4 o;
      o.x = f2bf(v[j].x); o.y = f2bf(v[j].y); o.z = f2bf(v[j].z); o.w = f2bf(v[j].w);
      ((u16x4*)(Acat + (size_t)b * KCAT + COMP))[l16 * 4 + j] = o;
    }
  }
}

// ---------------- dense 128x128 bf16 MFMA GEMM, B in [N][K] layout, K-split via blockIdx.z ----------------
// EPI: 0 = write bf16, 4 = atomicAdd f32
template<int EPI>
__global__ __launch_bounds__(256, 2)
void gemm_bt(const u16* __restrict__ A, int lda,
             const u16* __restrict__ B, int ldb,
             void* __restrict__ Cout, int ldc,
             int ktlen){
  __shared__ u16 Ab[2][128 * 64];
  __shared__ u16 Bb[2][128 * 64];

  const int t    = threadIdx.x;
  const int wv   = t >> 6;
  const int lane = t & 63;
  const int cx   = blockIdx.x;
  const int ry   = blockIdx.y;
  const int kt0  = blockIdx.z * ktlen;
  const int wr = wv >> 1, wc = wv & 1;
  const int l15 = lane & 15, lq = lane >> 4;

  auto stage = [&](int buf, int kt){
    const int k0 = (kt0 + kt) << 6;
    #pragma unroll
    for (int it = 0; it < 4; ++it){
      int G = it * 256 + wv * 64 + lane;
      int row = G >> 3;
      int g = (G & 7) ^ (row & 7);
      async16(A + (size_t)(ry * 128 + row) * lda + k0 + g * 8, &Ab[buf][(it * 256 + wv * 64) * 8]);
    }
    #pragma unroll
    for (int it = 0; it < 4; ++it){
      int G = it * 256 + wv * 64 + lane;
      int row = G >> 3;
      int g = (G & 7) ^ (row & 7);
      async16(B + (size_t)(cx * 128 + row) * ldb + k0 + g * 8, &Bb[buf][(it * 256 + wv * 64) * 8]);
    }
  };

  f32x4 acc[4][4];
  #pragma unroll
  for (int i = 0; i < 4; ++i)
    #pragma unroll
    for (int j = 0; j < 4; ++j){
      f32x4 z = {0.f, 0.f, 0.f, 0.f};
      acc[i][j] = z;
    }

  stage(0, 0);
  for (int kt = 0; kt < ktlen; ++kt){
    const int cur = kt & 1;
    if (kt + 1 < ktlen){
      stage(cur ^ 1, kt + 1);
      __builtin_amdgcn_sched_barrier(0);
      asm volatile("s_waitcnt vmcnt(8)" ::: "memory");
    } else {
      __builtin_amdgcn_sched_barrier(0);
      asm volatile("s_waitcnt vmcnt(0)" ::: "memory");
    }
    MEMFENCE(); __builtin_amdgcn_s_barrier(); MEMFENCE();

    #pragma unroll
    for (int kk = 0; kk < 2; ++kk){
      s16x8 af[4], bfr[4];
      #pragma unroll
      for (int i = 0; i < 4; ++i){
        int row = wr * 64 + i * 16 + l15;
        int sg  = (kk * 4 + lq) ^ (row & 7);
        af[i] = *(const s16x8*)&Ab[cur][row * 64 + sg * 8];
      }
      #pragma unroll
      for (int j = 0; j < 4; ++j){
        int row = wc * 64 + j * 16 + l15;
        int sg  = (kk * 4 + lq) ^ (row & 7);
        bfr[j] = *(const s16x8*)&Bb[cur][row * 64 + sg * 8];
      }
      #pragma unroll
      for (int i = 0; i < 4; ++i)
        #pragma unroll
        for (int j = 0; j < 4; ++j)
          acc[i][j] = __builtin_amdgcn_mfma_f32_16x16x32_bf16(af[i], bfr[j], acc[i][j], 0, 0, 0);
    }

    MEMFENCE(); __builtin_amdgcn_s_barrier(); MEMFENCE();
  }

  #pragma unroll
  for (int i = 0; i < 4; ++i){
    #pragma unroll
    for (int j = 0; j < 4; ++j){
      int rloc = wr * 64 + i * 16 + lq * 4;
      int col  = cx * 128 + wc * 64 + j * 16 + l15;
      #pragma unroll
      for (int r = 0; r < 4; ++r){
        int rit = rloc + r;
        if (EPI == 0){
          ((u16*)Cout)[(size_t)(ry * 128 + rit) * ldc + col] = f2bf(acc[i][j][r]);
        } else {
          atomicAdd((float*)Cout + (size_t)(ry * 128 + rit) * ldc + col, acc[i][j][r]);
        }
      }
    }
  }
}

// ---------------- reduce_cast: comp_f32 [8192][512] -> Acat bf16 cols [0,512) ----------------
__global__ void reduce_cast(const float* __restrict__ P, u16* __restrict__ Acat){
  const int n = B_TOK * COMP / 4;
  for (int i = blockIdx.x * blockDim.x + threadIdx.x; i < n; i += gridDim.x * blockDim.x){
    int row = i >> 7;            // 128 quads per row
    int c   = i & 127;
    fvec4 v = ((const fvec4*)P)[i];
    u16x4 o; o.x = f2bf(v.x); o.y = f2bf(v.y); o.z = f2bf(v.z); o.w = f2bf(v.w);
    ((u16x4*)(Acat + (size_t)row * KCAT))[c] = o;
  }
}

// ---------------- fused grouped GEMM: out = Acat[gathered] @ [D^T || W_e^T], K=768 ----------------
__global__ __launch_bounds__(256, 2)
void gemm_fused(const u16* __restrict__ Acat, const u16* __restrict__ Db,
                const u16* __restrict__ Wt, float* __restrict__ out,
                const int* __restrict__ counts, const int* __restrict__ tok_list){
  __shared__ u16 Ab[2][128 * 64];
  __shared__ u16 Bb[2][128 * 64];
  __shared__ int rowtok[128];

  const int t    = threadIdx.x;
  const int wv   = t >> 6;
  const int lane = t & 63;
  const int cx   = blockIdx.x;
  const int e    = blockIdx.z;
  const int Me   = counts[e];
  const u16* Wte = Wt + (size_t)e * OUTF * FSZ;
  const int KT   = KCAT >> 6;   // 12
  const int wr = wv >> 1, wc = wv & 1;
  const int l15 = lane & 15, lq = lane >> 4;

  for (int ry = blockIdx.y; ry * 128 < Me; ry += (int)gridDim.y){
    if (t < 128){
      int r  = ry * 128 + t;
      int rc = (r < Me) ? r : (Me - 1);
      rowtok[t] = tok_list[e * B_TOK + rc];
    }
    __syncthreads();

    auto stage = [&](int buf, int kt){
      #pragma unroll
      for (int it = 0; it < 4; ++it){
        int G = it * 256 + wv * 64 + lane;
        int row = G >> 3;
        int g = (G & 7) ^ (row & 7);
        async16(Acat + (size_t)rowtok[row] * KCAT + kt * 64 + g * 8, &Ab[buf][(it * 256 + wv * 64) * 8]);
      }
      #pragma unroll
      for (int it = 0; it < 4; ++it){
        int G = it * 256 + wv * 64 + lane;
        int row = G >> 3;
        int g = (G & 7) ^ (row & 7);
        const u16* src;
        if (kt < 8) src = Db  + (size_t)(cx * 128 + row) * COMP + kt * 64 + g * 8;
        else        src = Wte + (size_t)(cx * 128 + row) * FSZ  + (kt - 8) * 64 + g * 8;
        async16(src, &Bb[buf][(it * 256 + wv * 64) * 8]);
      }
    };

    f32x4 acc[4][4];
    #pragma unroll
    for (int i = 0; i < 4; ++i)
      #pragma unroll
      for (int j = 0; j < 4; ++j){
        f32x4 z = {0.f, 0.f, 0.f, 0.f};
        acc[i][j] = z;
      }

    stage(0, 0);
    for (int kt = 0; kt < KT; ++kt){
      const int cur = kt & 1;
      if (kt + 1 < KT){
        stage(cur ^ 1, kt + 1);
        __builtin_amdgcn_sched_barrier(0);
        asm volatile("s_waitcnt vmcnt(8)" ::: "memory");
      } else {
        __builtin_amdgcn_sched_barrier(0);
        asm volatile("s_waitcnt vmcnt(0)" ::: "memory");
      }
      MEMFENCE(); __builtin_amdgcn_s_barrier(); MEMFENCE();

      #pragma unroll
      for (int kk = 0; kk < 2; ++kk){
        s16x8 af[4], bfr[4];
        #pragma unroll
        for (int i = 0; i < 4; ++i){
          int row = wr * 64 + i * 16 + l15;
          int sg  = (kk * 4 + lq) ^ (row & 7);
          af[i] = *(const s16x8*)&Ab[cur][row * 64 + sg * 8];
        }
        #pragma unroll
        for (int j = 0; j < 4; ++j){
          int row = wc * 64 + j * 16 + l15;
          int sg  = (kk * 4 + lq) ^ (row & 7);
          bfr[j] = *(const s16x8*)&Bb[cur][row * 64 + sg * 8];
        }
        #pragma unroll
        for (int i = 0; i < 4; ++i)
          #pragma unroll
          for (int j = 0; j < 4; ++j)
            acc[i][j] = __builtin_amdgcn_mfma_f32_16x16x32_bf16(af[i], bfr[j], acc[i][j], 0, 0, 0);
      }

      MEMFENCE(); __builtin_amdgcn_s_barrier(); MEMFENCE();
    }

    // epilogue: plain f32 scatter-store (each token row written exactly once;
    // padded duplicate rows re-store identical values — benign)
    #pragma unroll
    for (int i = 0; i < 4; ++i){
      #pragma unroll
      for (int j = 0; j < 4; ++j){
        int rloc = wr * 64 + i * 16 + lq * 4;
        int col  = cx * 128 + wc * 64 + j * 16 + l15;
        #pragma unroll
        for (int r = 0; r < 4; ++r){
          int rit = rloc + r;
          out[(size_t)rowtok[rit] * OUTF + col] = acc[i][j][r];
        }
      }
    }
    __syncthreads();
  }
}

// ---------------- host launcher ----------------
extern "C" void kernel_launch(void* const* d_in, const int* in_sizes, int n_in,
                              void* d_out, int out_size, void* d_ws, size_t ws_size,
                              hipStream_t stream){
  const float* x  = (const float*)d_in[0];
  const float* sw = (const float*)d_in[1];
  const float* W  = (const float*)d_in[2];
  const float* C  = (const float*)d_in[3];
  const float* D  = (const float*)d_in[4];
  float* out = (float*)d_out;

  char* w = (char*)d_ws;
  size_t off = 0;
  auto alloc = [&](size_t bytes) -> void* {
    void* p = w + off;
    off += (bytes + 255) & ~(size_t)255;
    return p;
  };
  u16* masked = (u16*)alloc((size_t)B_TOK * INF * 2);        // 64 MiB
  u16* Acat   = (u16*)alloc((size_t)B_TOK * KCAT * 2);       // 12 MiB
  u16* Cb     = (u16*)alloc((size_t)COMP * INF * 2);         // 4 MiB
  u16* Db     = (u16*)alloc((size_t)OUTF * COMP * 2);        // 4 MiB
  u16* Wt     = (u16*)alloc((size_t)NFRAG * OUTF * FSZ * 2); // 32 MiB
  int* counts = (int*)alloc(NFRAG * sizeof(int));
  int* toks   = (int*)alloc((size_t)NFRAG * B_TOK * sizeof(int));
  size_t base_off = off;
  float* comp_f32 = (float*)alloc((size_t)B_TOK * COMP * sizeof(float)); // +16 MiB
  const bool split = (off <= ws_size);
  (void)base_off;

  hipMemsetAsync(counts, 0, NFRAG * sizeof(int), stream);

  cast_bf16<<<2048, 256, 0, stream>>>(C, Cb, (COMP * INF) / 4);
  cast_bf16<<<2048, 256, 0, stream>>>(D, Db, (OUTF * COMP) / 4);
  transpose_cast_w<<<dim3(64, 4, 16), 256, 0, stream>>>(W, Wt);
  prep_kernel<<<B_TOK, 256, 0, stream>>>(x, sw, masked, Acat, counts, toks);

  if (split){
    // split-K=2: 512 blocks (2/CU, LDS-capped), atomicAdd f32 partial sums
    hipMemsetAsync(comp_f32, 0, (size_t)B_TOK * COMP * sizeof(float), stream);
    gemm_bt<4><<<dim3(COMP / 128, B_TOK / 128, 2), 256, 0, stream>>>(
        masked, INF, Cb, INF, comp_f32, COMP, 32);
    reduce_cast<<<1024, 256, 0, stream>>>(comp_f32, Acat);
  } else {
    gemm_bt<0><<<dim3(COMP / 128, B_TOK / 128, 1), 256, 0, stream>>>(
        masked, INF, Cb, INF, Acat, KCAT, 64);
  }

  // fused: out = Acat[token-gathered] @ [D^T || W_e^T]  (K=768), written once
  gemm_fused<<<dim3(OUTF / 128, 8, NFRAG), 256, 0, stream>>>(
      Acat, Db, Wt, out, counts, toks);
}

// Round 4
// 512.649 us; speedup vs baseline: 1.1882x; 1.0008x over previous
//
#include <hip/hip_runtime.h>
#include <stdint.h>

typedef unsigned short u16;
typedef __attribute__((ext_vector_type(4))) float  fvec4;
typedef __attribute__((ext_vector_type(4))) float  f32x4;
typedef __attribute__((ext_vector_type(8))) short  s16x8;
typedef __attribute__((ext_vector_type(4))) u16    u16x4;

#define AS1 __attribute__((address_space(1)))
#define AS3 __attribute__((address_space(3)))
#define MEMFENCE() asm volatile("" ::: "memory")

#define B_TOK   8192
#define NFRAG   16
#define FSZ     256
#define INF     4096
#define OUTF    4096
#define COMP    512
#define KCAT    768      // COMP + FSZ

__device__ __forceinline__ u16 f2bf(float f){
  union { float fv; unsigned int u; } v; v.fv = f;
  unsigned int u = v.u;
  u += 0x7fffu + ((u >> 16) & 1u);
  return (u16)(u >> 16);
}

__device__ __forceinline__ void async16(const void* g, void* l){
  __builtin_amdgcn_global_load_lds((const AS1 unsigned int*)g, (AS3 unsigned int*)l, 16, 0, 0);
}

// ---------------- elementwise f32 -> bf16 cast (same layout) ----------------
__global__ void cast_bf16(const float* __restrict__ in, u16* __restrict__ out, int nquads){
  for (int i = blockIdx.x * blockDim.x + threadIdx.x; i < nquads; i += gridDim.x * blockDim.x){
    fvec4 v = ((const fvec4*)in)[i];
    u16x4 o; o.x = f2bf(v.x); o.y = f2bf(v.y); o.z = f2bf(v.z); o.w = f2bf(v.w);
    ((u16x4*)out)[i] = o;
  }
}

// ------------- transpose-cast expert weights: [16][256][4096] f32 -> [16][4096][256] bf16 -------------
__global__ void transpose_cast_w(const float* __restrict__ W, u16* __restrict__ Wt){
  __shared__ u16 ldsT[64][72];
  const int e  = blockIdx.z;
  const int kt = blockIdx.y;
  const int nt = blockIdx.x;
  const int t  = threadIdx.x;
  const float* Wb = W + (size_t)e * FSZ * OUTF;

  const int tr = t >> 4;
  const int tc = t & 15;
  #pragma unroll
  for (int it = 0; it < 4; ++it){
    int k = it * 16 + tr;
    fvec4 v = *(const fvec4*)(Wb + (size_t)(kt * 64 + k) * OUTF + nt * 64 + tc * 4);
    ldsT[tc*4 + 0][k] = f2bf(v.x);
    ldsT[tc*4 + 1][k] = f2bf(v.y);
    ldsT[tc*4 + 2][k] = f2bf(v.z);
    ldsT[tc*4 + 3][k] = f2bf(v.w);
  }
  __syncthreads();
  u16* Wtb = Wt + (size_t)e * OUTF * FSZ;
  const int nr = t >> 3;
  const int nc = t & 7;
  #pragma unroll
  for (int it = 0; it < 2; ++it){
    int n = it * 32 + nr;
    s16x8 val = *(const s16x8*)&ldsT[n][nc * 8];
    *(s16x8*)(Wtb + (size_t)(nt * 64 + n) * FSZ + kt * 64 + nc * 8) = val;
  }
}

// ---------------- prep: selector + argmax + bucket scatter + masked/xsel bf16 ----------------
// Wave-coalesced: thread t handles quad j*256 + t (j=0..3); wave w owns fragment j*4+w.
// xsel is written into Acat columns [512,768) with row stride KCAT.
__global__ void prep_kernel(const float* __restrict__ x, const float* __restrict__ sw,
                            u16* __restrict__ masked, u16* __restrict__ Acat,
                            int* __restrict__ counts, int* __restrict__ tok_list){
  const int b = blockIdx.x;
  const int t = threadIdx.x;
  const int w = t >> 6;                   // wave 0..3
  const int l = t & 63;                   // lane
  const float* xr = x + (size_t)b * INF;
  const fvec4* xq  = (const fvec4*)xr;
  const fvec4* swq = (const fvec4*)sw;    // [16][64] quads

  fvec4 v[4];
  float p[4];
  #pragma unroll
  for (int j = 0; j < 4; ++j){
    v[j] = xq[j * 256 + t];               // lane-contiguous 1KB per wave
    fvec4 wv = swq[(j * 4 + w) * 64 + l]; // selector weights for fragment j*4+w
    p[j] = v[j].x * wv.x + v[j].y * wv.y + v[j].z * wv.z + v[j].w * wv.w;
  }
  // 64-lane butterfly reduce, all 4 partials
  #pragma unroll
  for (int m = 1; m < 64; m <<= 1){
    #pragma unroll
    for (int j = 0; j < 4; ++j) p[j] += __shfl_xor(p[j], m, 64);
  }

  __shared__ float sc[NFRAG];
  if (l == 0){
    #pragma unroll
    for (int j = 0; j < 4; ++j) sc[j * 4 + w] = p[j];
  }
  __syncthreads();

  // redundant argmax on every thread (strict > from 0 == numpy first-max)
  float best = sc[0]; int sel = 0;
  #pragma unroll
  for (int i = 1; i < NFRAG; ++i){ if (sc[i] > best){ best = sc[i]; sel = i; } }

  if (t == 0){
    int pos = atomicAdd(&counts[sel], 1);
    tok_list[sel * B_TOK + pos] = b;
  }

  u16x4* mq = (u16x4*)(masked + (size_t)b * INF);
  #pragma unroll
  for (int j = 0; j < 4; ++j){
    const bool insel = ((j * 4 + w) == sel);
    u16x4 o;
    o.x = insel ? (u16)0 : f2bf(v[j].x);
    o.y = insel ? (u16)0 : f2bf(v[j].y);
    o.z = insel ? (u16)0 : f2bf(v[j].z);
    o.w = insel ? (u16)0 : f2bf(v[j].w);
    mq[j * 256 + t] = o;                  // wave-contiguous 512B
    if (insel){
      u16x4 s;
      s.x = f2bf(v[j].x); s.y = f2bf(v[j].y); s.z = f2bf(v[j].z); s.w = f2bf(v[j].w);
      ((u16x4*)(Acat + (size_t)b * KCAT + COMP))[l] = s;   // 64 lanes x 8B contiguous
    }
  }
}

// ---------------- dense 128x128 bf16 MFMA GEMM, B in [N][K] layout, K-split via blockIdx.z ----------------
// EPI: 0 = write bf16, 4 = atomicAdd f32
template<int EPI>
__global__ __launch_bounds__(256, 2)
void gemm_bt(const u16* __restrict__ A, int lda,
             const u16* __restrict__ B, int ldb,
             void* __restrict__ Cout, int ldc,
             int ktlen){
  __shared__ u16 Ab[2][128 * 64];
  __shared__ u16 Bb[2][128 * 64];

  const int t    = threadIdx.x;
  const int wv   = t >> 6;
  const int lane = t & 63;
  const int cx   = blockIdx.x;
  const int ry   = blockIdx.y;
  const int kt0  = blockIdx.z * ktlen;
  const int wr = wv >> 1, wc = wv & 1;
  const int l15 = lane & 15, lq = lane >> 4;

  auto stage = [&](int buf, int kt){
    const int k0 = (kt0 + kt) << 6;
    #pragma unroll
    for (int it = 0; it < 4; ++it){
      int G = it * 256 + wv * 64 + lane;
      int row = G >> 3;
      int g = (G & 7) ^ (row & 7);
      async16(A + (size_t)(ry * 128 + row) * lda + k0 + g * 8, &Ab[buf][(it * 256 + wv * 64) * 8]);
    }
    #pragma unroll
    for (int it = 0; it < 4; ++it){
      int G = it * 256 + wv * 64 + lane;
      int row = G >> 3;
      int g = (G & 7) ^ (row & 7);
      async16(B + (size_t)(cx * 128 + row) * ldb + k0 + g * 8, &Bb[buf][(it * 256 + wv * 64) * 8]);
    }
  };

  f32x4 acc[4][4];
  #pragma unroll
  for (int i = 0; i < 4; ++i)
    #pragma unroll
    for (int j = 0; j < 4; ++j){
      f32x4 z = {0.f, 0.f, 0.f, 0.f};
      acc[i][j] = z;
    }

  stage(0, 0);
  for (int kt = 0; kt < ktlen; ++kt){
    const int cur = kt & 1;
    if (kt + 1 < ktlen){
      stage(cur ^ 1, kt + 1);
      __builtin_amdgcn_sched_barrier(0);
      asm volatile("s_waitcnt vmcnt(8)" ::: "memory");
    } else {
      __builtin_amdgcn_sched_barrier(0);
      asm volatile("s_waitcnt vmcnt(0)" ::: "memory");
    }
    MEMFENCE(); __builtin_amdgcn_s_barrier(); MEMFENCE();

    #pragma unroll
    for (int kk = 0; kk < 2; ++kk){
      s16x8 af[4], bfr[4];
      #pragma unroll
      for (int i = 0; i < 4; ++i){
        int row = wr * 64 + i * 16 + l15;
        int sg  = (kk * 4 + lq) ^ (row & 7);
        af[i] = *(const s16x8*)&Ab[cur][row * 64 + sg * 8];
      }
      #pragma unroll
      for (int j = 0; j < 4; ++j){
        int row = wc * 64 + j * 16 + l15;
        int sg  = (kk * 4 + lq) ^ (row & 7);
        bfr[j] = *(const s16x8*)&Bb[cur][row * 64 + sg * 8];
      }
      #pragma unroll
      for (int i = 0; i < 4; ++i)
        #pragma unroll
        for (int j = 0; j < 4; ++j)
          acc[i][j] = __builtin_amdgcn_mfma_f32_16x16x32_bf16(af[i], bfr[j], acc[i][j], 0, 0, 0);
    }

    MEMFENCE(); __builtin_amdgcn_s_barrier(); MEMFENCE();
  }

  #pragma unroll
  for (int i = 0; i < 4; ++i){
    #pragma unroll
    for (int j = 0; j < 4; ++j){
      int rloc = wr * 64 + i * 16 + lq * 4;
      int col  = cx * 128 + wc * 64 + j * 16 + l15;
      #pragma unroll
      for (int r = 0; r < 4; ++r){
        int rit = rloc + r;
        if (EPI == 0){
          ((u16*)Cout)[(size_t)(ry * 128 + rit) * ldc + col] = f2bf(acc[i][j][r]);
        } else {
          atomicAdd((float*)Cout + (size_t)(ry * 128 + rit) * ldc + col, acc[i][j][r]);
        }
      }
    }
  }
}

// ---------------- reduce_cast: comp_f32 [8192][512] -> Acat bf16 cols [0,512) ----------------
__global__ void reduce_cast(const float* __restrict__ P, u16* __restrict__ Acat){
  const int n = B_TOK * COMP / 4;
  for (int i = blockIdx.x * blockDim.x + threadIdx.x; i < n; i += gridDim.x * blockDim.x){
    int row = i >> 7;            // 128 quads per row
    int c   = i & 127;
    fvec4 v = ((const fvec4*)P)[i];
    u16x4 o; o.x = f2bf(v.x); o.y = f2bf(v.y); o.z = f2bf(v.z); o.w = f2bf(v.w);
    ((u16x4*)(Acat + (size_t)row * KCAT))[c] = o;
  }
}

// ---------------- fused grouped GEMM: out = Acat[gathered] @ [D^T || W_e^T], K=768 ----------------
__global__ __launch_bounds__(256, 2)
void gemm_fused(const u16* __restrict__ Acat, const u16* __restrict__ Db,
                const u16* __restrict__ Wt, float* __restrict__ out,
                const int* __restrict__ counts, const int* __restrict__ tok_list){
  __shared__ u16 Ab[2][128 * 64];
  __shared__ u16 Bb[2][128 * 64];
  __shared__ int rowtok[128];

  const int t    = threadIdx.x;
  const int wv   = t >> 6;
  const int lane = t & 63;
  const int cx   = blockIdx.x;
  const int e    = blockIdx.z;
  const int Me   = counts[e];
  const u16* Wte = Wt + (size_t)e * OUTF * FSZ;
  const int KT   = KCAT >> 6;   // 12
  const int wr = wv >> 1, wc = wv & 1;
  const int l15 = lane & 15, lq = lane >> 4;

  for (int ry = blockIdx.y; ry * 128 < Me; ry += (int)gridDim.y){
    if (t < 128){
      int r  = ry * 128 + t;
      int rc = (r < Me) ? r : (Me - 1);
      rowtok[t] = tok_list[e * B_TOK + rc];
    }
    __syncthreads();

    auto stage = [&](int buf, int kt){
      #pragma unroll
      for (int it = 0; it < 4; ++it){
        int G = it * 256 + wv * 64 + lane;
        int row = G >> 3;
        int g = (G & 7) ^ (row & 7);
        async16(Acat + (size_t)rowtok[row] * KCAT + kt * 64 + g * 8, &Ab[buf][(it * 256 + wv * 64) * 8]);
      }
      #pragma unroll
      for (int it = 0; it < 4; ++it){
        int G = it * 256 + wv * 64 + lane;
        int row = G >> 3;
        int g = (G & 7) ^ (row & 7);
        const u16* src;
        if (kt < 8) src = Db  + (size_t)(cx * 128 + row) * COMP + kt * 64 + g * 8;
        else        src = Wte + (size_t)(cx * 128 + row) * FSZ  + (kt - 8) * 64 + g * 8;
        async16(src, &Bb[buf][(it * 256 + wv * 64) * 8]);
      }
    };

    f32x4 acc[4][4];
    #pragma unroll
    for (int i = 0; i < 4; ++i)
      #pragma unroll
      for (int j = 0; j < 4; ++j){
        f32x4 z = {0.f, 0.f, 0.f, 0.f};
        acc[i][j] = z;
      }

    stage(0, 0);
    for (int kt = 0; kt < KT; ++kt){
      const int cur = kt & 1;
      if (kt + 1 < KT){
        stage(cur ^ 1, kt + 1);
        __builtin_amdgcn_sched_barrier(0);
        asm volatile("s_waitcnt vmcnt(8)" ::: "memory");
      } else {
        __builtin_amdgcn_sched_barrier(0);
        asm volatile("s_waitcnt vmcnt(0)" ::: "memory");
      }
      MEMFENCE(); __builtin_amdgcn_s_barrier(); MEMFENCE();

      #pragma unroll
      for (int kk = 0; kk < 2; ++kk){
        s16x8 af[4], bfr[4];
        #pragma unroll
        for (int i = 0; i < 4; ++i){
          int row = wr * 64 + i * 16 + l15;
          int sg  = (kk * 4 + lq) ^ (row & 7);
          af[i] = *(const s16x8*)&Ab[cur][row * 64 + sg * 8];
        }
        #pragma unroll
        for (int j = 0; j < 4; ++j){
          int row = wc * 64 + j * 16 + l15;
          int sg  = (kk * 4 + lq) ^ (row & 7);
          bfr[j] = *(const s16x8*)&Bb[cur][row * 64 + sg * 8];
        }
        #pragma unroll
        for (int i = 0; i < 4; ++i)
          #pragma unroll
          for (int j = 0; j < 4; ++j)
            acc[i][j] = __builtin_amdgcn_mfma_f32_16x16x32_bf16(af[i], bfr[j], acc[i][j], 0, 0, 0);
      }

      MEMFENCE(); __builtin_amdgcn_s_barrier(); MEMFENCE();
    }

    // epilogue: plain f32 scatter-store (each token row written exactly once;
    // padded duplicate rows re-store identical values — benign)
    #pragma unroll
    for (int i = 0; i < 4; ++i){
      #pragma unroll
      for (int j = 0; j < 4; ++j){
        int rloc = wr * 64 + i * 16 + lq * 4;
        int col  = cx * 128 + wc * 64 + j * 16 + l15;
        #pragma unroll
        for (int r = 0; r < 4; ++r){
          int rit = rloc + r;
          out[(size_t)rowtok[rit] * OUTF + col] = acc[i][j][r];
        }
      }
    }
    __syncthreads();
  }
}

// ---------------- host launcher ----------------
extern "C" void kernel_launch(void* const* d_in, const int* in_sizes, int n_in,
                              void* d_out, int out_size, void* d_ws, size_t ws_size,
                              hipStream_t stream){
  const float* x  = (const float*)d_in[0];
  const float* sw = (const float*)d_in[1];
  const float* W  = (const float*)d_in[2];
  const float* C  = (const float*)d_in[3];
  const float* D  = (const float*)d_in[4];
  float* out = (float*)d_out;

  char* w = (char*)d_ws;
  size_t off = 0;
  auto alloc = [&](size_t bytes) -> void* {
    void* p = w + off;
    off += (bytes + 255) & ~(size_t)255;
    return p;
  };
  u16* masked = (u16*)alloc((size_t)B_TOK * INF * 2);        // 64 MiB
  u16* Acat   = (u16*)alloc((size_t)B_TOK * KCAT * 2);       // 12 MiB
  u16* Cb     = (u16*)alloc((size_t)COMP * INF * 2);         // 4 MiB
  u16* Db     = (u16*)alloc((size_t)OUTF * COMP * 2);        // 4 MiB
  u16* Wt     = (u16*)alloc((size_t)NFRAG * OUTF * FSZ * 2); // 32 MiB
  int* counts = (int*)alloc(NFRAG * sizeof(int));
  int* toks   = (int*)alloc((size_t)NFRAG * B_TOK * sizeof(int));
  float* comp_f32 = (float*)alloc((size_t)B_TOK * COMP * sizeof(float)); // +16 MiB
  const bool split = (off <= ws_size);

  hipMemsetAsync(counts, 0, NFRAG * sizeof(int), stream);

  cast_bf16<<<2048, 256, 0, stream>>>(C, Cb, (COMP * INF) / 4);
  cast_bf16<<<2048, 256, 0, stream>>>(D, Db, (OUTF * COMP) / 4);
  transpose_cast_w<<<dim3(64, 4, 16), 256, 0, stream>>>(W, Wt);
  prep_kernel<<<B_TOK, 256, 0, stream>>>(x, sw, masked, Acat, counts, toks);

  if (split){
    // split-K=2: 512 blocks (2/CU, LDS-capped), atomicAdd f32 partial sums
    hipMemsetAsync(comp_f32, 0, (size_t)B_TOK * COMP * sizeof(float), stream);
    gemm_bt<4><<<dim3(COMP / 128, B_TOK / 128, 2), 256, 0, stream>>>(
        masked, INF, Cb, INF, comp_f32, COMP, 32);
    reduce_cast<<<1024, 256, 0, stream>>>(comp_f32, Acat);
  } else {
    gemm_bt<0><<<dim3(COMP / 128, B_TOK / 128, 1), 256, 0, stream>>>(
        masked, INF, Cb, INF, Acat, KCAT, 64);
  }

  // fused: out = Acat[token-gathered] @ [D^T || W_e^T]  (K=768), written once
  gemm_fused<<<dim3(OUTF / 128, 8, NFRAG), 256, 0, stream>>>(
      Acat, Db, Wt, out, counts, toks);
}

// Round 5
// 471.209 us; speedup vs baseline: 1.2927x; 1.0879x over previous
//
#include <hip/hip_runtime.h>
#include <stdint.h>

typedef unsigned short u16;
typedef __attribute__((ext_vector_type(4))) float  fvec4;
typedef __attribute__((ext_vector_type(4))) float  f32x4;
typedef __attribute__((ext_vector_type(8))) short  s16x8;
typedef __attribute__((ext_vector_type(4))) u16    u16x4;

#define AS1 __attribute__((address_space(1)))
#define AS3 __attribute__((address_space(3)))
#define MEMFENCE() asm volatile("" ::: "memory")

#define B_TOK   8192
#define NFRAG   16
#define FSZ     256
#define INF     4096
#define OUTF    4096
#define COMP    512
#define KCAT    768      // COMP + FSZ
#define CSTRIDE 64       // counts padded to 256B per expert (separate cache lines/channels)

__device__ __forceinline__ u16 f2bf(float f){
  union { float fv; unsigned int u; } v; v.fv = f;
  unsigned int u = v.u;
  u += 0x7fffu + ((u >> 16) & 1u);
  return (u16)(u >> 16);
}

__device__ __forceinline__ void async16(const void* g, void* l){
  __builtin_amdgcn_global_load_lds((const AS1 unsigned int*)g, (AS3 unsigned int*)l, 16, 0, 0);
}

// ---------------- elementwise f32 -> bf16 cast (same layout) ----------------
__global__ void cast_bf16(const float* __restrict__ in, u16* __restrict__ out, int nquads){
  for (int i = blockIdx.x * blockDim.x + threadIdx.x; i < nquads; i += gridDim.x * blockDim.x){
    fvec4 v = ((const fvec4*)in)[i];
    u16x4 o; o.x = f2bf(v.x); o.y = f2bf(v.y); o.z = f2bf(v.z); o.w = f2bf(v.w);
    ((u16x4*)out)[i] = o;
  }
}

// ------------- transpose-cast expert weights: [16][256][4096] f32 -> [16][4096][256] bf16 -------------
__global__ void transpose_cast_w(const float* __restrict__ W, u16* __restrict__ Wt){
  __shared__ u16 ldsT[64][72];
  const int e  = blockIdx.z;
  const int kt = blockIdx.y;
  const int nt = blockIdx.x;
  const int t  = threadIdx.x;
  const float* Wb = W + (size_t)e * FSZ * OUTF;

  const int tr = t >> 4;
  const int tc = t & 15;
  #pragma unroll
  for (int it = 0; it < 4; ++it){
    int k = it * 16 + tr;
    fvec4 v = *(const fvec4*)(Wb + (size_t)(kt * 64 + k) * OUTF + nt * 64 + tc * 4);
    ldsT[tc*4 + 0][k] = f2bf(v.x);
    ldsT[tc*4 + 1][k] = f2bf(v.y);
    ldsT[tc*4 + 2][k] = f2bf(v.z);
    ldsT[tc*4 + 3][k] = f2bf(v.w);
  }
  __syncthreads();
  u16* Wtb = Wt + (size_t)e * OUTF * FSZ;
  const int nr = t >> 3;
  const int nc = t & 7;
  #pragma unroll
  for (int it = 0; it < 2; ++it){
    int n = it * 32 + nr;
    s16x8 val = *(const s16x8*)&ldsT[n][nc * 8];
    *(s16x8*)(Wtb + (size_t)(nt * 64 + n) * FSZ + kt * 64 + nc * 8) = val;
  }
}

// ---------------- prep: selector + argmax + bucket scatter + masked/xsel bf16 ----------------
// Wave-coalesced: thread t handles quad j*256 + t (j=0..3); wave w owns fragment j*4+w.
// xsel is written into Acat columns [512,768) with row stride KCAT.
__global__ void prep_kernel(const float* __restrict__ x, const float* __restrict__ sw,
                            u16* __restrict__ masked, u16* __restrict__ Acat,
                            int* __restrict__ counts, int* __restrict__ tok_list){
  const int b = blockIdx.x;
  const int t = threadIdx.x;
  const int w = t >> 6;                   // wave 0..3
  const int l = t & 63;                   // lane
  const float* xr = x + (size_t)b * INF;
  const fvec4* xq  = (const fvec4*)xr;
  const fvec4* swq = (const fvec4*)sw;    // [16][64] quads

  fvec4 v[4];
  float p[4];
  #pragma unroll
  for (int j = 0; j < 4; ++j){
    v[j] = xq[j * 256 + t];               // lane-contiguous 1KB per wave
    fvec4 wv = swq[(j * 4 + w) * 64 + l]; // selector weights for fragment j*4+w
    p[j] = v[j].x * wv.x + v[j].y * wv.y + v[j].z * wv.z + v[j].w * wv.w;
  }
  // 64-lane butterfly reduce, all 4 partials
  #pragma unroll
  for (int m = 1; m < 64; m <<= 1){
    #pragma unroll
    for (int j = 0; j < 4; ++j) p[j] += __shfl_xor(p[j], m, 64);
  }

  __shared__ float sc[NFRAG];
  if (l == 0){
    #pragma unroll
    for (int j = 0; j < 4; ++j) sc[j * 4 + w] = p[j];
  }
  __syncthreads();

  // redundant argmax on every thread (strict > from 0 == numpy first-max)
  float best = sc[0]; int sel = 0;
  #pragma unroll
  for (int i = 1; i < NFRAG; ++i){ if (sc[i] > best){ best = sc[i]; sel = i; } }

  if (t == 0){
    int pos = atomicAdd(&counts[sel * CSTRIDE], 1);
    tok_list[sel * B_TOK + pos] = b;
  }

  u16x4* mq = (u16x4*)(masked + (size_t)b * INF);
  #pragma unroll
  for (int j = 0; j < 4; ++j){
    const bool insel = ((j * 4 + w) == sel);
    u16x4 o;
    o.x = insel ? (u16)0 : f2bf(v[j].x);
    o.y = insel ? (u16)0 : f2bf(v[j].y);
    o.z = insel ? (u16)0 : f2bf(v[j].z);
    o.w = insel ? (u16)0 : f2bf(v[j].w);
    mq[j * 256 + t] = o;                  // wave-contiguous 512B
    if (insel){
      u16x4 s;
      s.x = f2bf(v[j].x); s.y = f2bf(v[j].y); s.z = f2bf(v[j].z); s.w = f2bf(v[j].w);
      ((u16x4*)(Acat + (size_t)b * KCAT + COMP))[l] = s;   // 64 lanes x 8B contiguous
    }
  }
}

// ---------------- dense 128x128 bf16 MFMA GEMM, B in [N][K] layout, K-split via blockIdx.z ----------------
// EPI: 0 = write bf16, 4 = atomicAdd f32
template<int EPI>
__global__ __launch_bounds__(256, 2)
void gemm_bt(const u16* __restrict__ A, int lda,
             const u16* __restrict__ B, int ldb,
             void* __restrict__ Cout, int ldc,
             int ktlen){
  __shared__ u16 Ab[2][128 * 64];
  __shared__ u16 Bb[2][128 * 64];

  const int t    = threadIdx.x;
  const int wv   = t >> 6;
  const int lane = t & 63;
  const int cx   = blockIdx.x;
  const int ry   = blockIdx.y;
  const int kt0  = blockIdx.z * ktlen;
  const int wr = wv >> 1, wc = wv & 1;
  const int l15 = lane & 15, lq = lane >> 4;

  auto stage = [&](int buf, int kt){
    const int k0 = (kt0 + kt) << 6;
    #pragma unroll
    for (int it = 0; it < 4; ++it){
      int G = it * 256 + wv * 64 + lane;
      int row = G >> 3;
      int g = (G & 7) ^ (row & 7);
      async16(A + (size_t)(ry * 128 + row) * lda + k0 + g * 8, &Ab[buf][(it * 256 + wv * 64) * 8]);
    }
    #pragma unroll
    for (int it = 0; it < 4; ++it){
      int G = it * 256 + wv * 64 + lane;
      int row = G >> 3;
      int g = (G & 7) ^ (row & 7);
      async16(B + (size_t)(cx * 128 + row) * ldb + k0 + g * 8, &Bb[buf][(it * 256 + wv * 64) * 8]);
    }
  };

  f32x4 acc[4][4];
  #pragma unroll
  for (int i = 0; i < 4; ++i)
    #pragma unroll
    for (int j = 0; j < 4; ++j){
      f32x4 z = {0.f, 0.f, 0.f, 0.f};
      acc[i][j] = z;
    }

  stage(0, 0);
  for (int kt = 0; kt < ktlen; ++kt){
    const int cur = kt & 1;
    if (kt + 1 < ktlen){
      stage(cur ^ 1, kt + 1);
      __builtin_amdgcn_sched_barrier(0);
      asm volatile("s_waitcnt vmcnt(8)" ::: "memory");
    } else {
      __builtin_amdgcn_sched_barrier(0);
      asm volatile("s_waitcnt vmcnt(0)" ::: "memory");
    }
    MEMFENCE(); __builtin_amdgcn_s_barrier(); MEMFENCE();

    #pragma unroll
    for (int kk = 0; kk < 2; ++kk){
      s16x8 af[4], bfr[4];
      #pragma unroll
      for (int i = 0; i < 4; ++i){
        int row = wr * 64 + i * 16 + l15;
        int sg  = (kk * 4 + lq) ^ (row & 7);
        af[i] = *(const s16x8*)&Ab[cur][row * 64 + sg * 8];
      }
      #pragma unroll
      for (int j = 0; j < 4; ++j){
        int row = wc * 64 + j * 16 + l15;
        int sg  = (kk * 4 + lq) ^ (row & 7);
        bfr[j] = *(const s16x8*)&Bb[cur][row * 64 + sg * 8];
      }
      #pragma unroll
      for (int i = 0; i < 4; ++i)
        #pragma unroll
        for (int j = 0; j < 4; ++j)
          acc[i][j] = __builtin_amdgcn_mfma_f32_16x16x32_bf16(af[i], bfr[j], acc[i][j], 0, 0, 0);
    }

    MEMFENCE(); __builtin_amdgcn_s_barrier(); MEMFENCE();
  }

  #pragma unroll
  for (int i = 0; i < 4; ++i){
    #pragma unroll
    for (int j = 0; j < 4; ++j){
      int rloc = wr * 64 + i * 16 + lq * 4;
      int col  = cx * 128 + wc * 64 + j * 16 + l15;
      #pragma unroll
      for (int r = 0; r < 4; ++r){
        int rit = rloc + r;
        if (EPI == 0){
          ((u16*)Cout)[(size_t)(ry * 128 + rit) * ldc + col] = f2bf(acc[i][j][r]);
        } else {
          atomicAdd((float*)Cout + (size_t)(ry * 128 + rit) * ldc + col, acc[i][j][r]);
        }
      }
    }
  }
}

// ---------------- reduce_cast: comp_f32 [8192][512] -> Acat bf16 cols [0,512) ----------------
__global__ void reduce_cast(const float* __restrict__ P, u16* __restrict__ Acat){
  const int n = B_TOK * COMP / 4;
  for (int i = blockIdx.x * blockDim.x + threadIdx.x; i < n; i += gridDim.x * blockDim.x){
    int row = i >> 7;            // 128 quads per row
    int c   = i & 127;
    fvec4 v = ((const fvec4*)P)[i];
    u16x4 o; o.x = f2bf(v.x); o.y = f2bf(v.y); o.z = f2bf(v.z); o.w = f2bf(v.w);
    ((u16x4*)(Acat + (size_t)row * KCAT))[c] = o;
  }
}

// ---------------- fused grouped GEMM: out = Acat[gathered] @ [D^T || W_e^T], K=768 ----------------
__global__ __launch_bounds__(256, 2)
void gemm_fused(const u16* __restrict__ Acat, const u16* __restrict__ Db,
                const u16* __restrict__ Wt, float* __restrict__ out,
                const int* __restrict__ counts, const int* __restrict__ tok_list){
  __shared__ u16 Ab[2][128 * 64];
  __shared__ u16 Bb[2][128 * 64];
  __shared__ int rowtok[128];

  const int t    = threadIdx.x;
  const int wv   = t >> 6;
  const int lane = t & 63;
  const int cx   = blockIdx.x;
  const int e    = blockIdx.z;
  const int Me   = counts[e * CSTRIDE];
  const u16* Wte = Wt + (size_t)e * OUTF * FSZ;
  const int KT   = KCAT >> 6;   // 12
  const int wr = wv >> 1, wc = wv & 1;
  const int l15 = lane & 15, lq = lane >> 4;

  for (int ry = blockIdx.y; ry * 128 < Me; ry += (int)gridDim.y){
    if (t < 128){
      int r  = ry * 128 + t;
      int rc = (r < Me) ? r : (Me - 1);
      rowtok[t] = tok_list[e * B_TOK + rc];
    }
    __syncthreads();

    auto stage = [&](int buf, int kt){
      #pragma unroll
      for (int it = 0; it < 4; ++it){
        int G = it * 256 + wv * 64 + lane;
        int row = G >> 3;
        int g = (G & 7) ^ (row & 7);
        async16(Acat + (size_t)rowtok[row] * KCAT + kt * 64 + g * 8, &Ab[buf][(it * 256 + wv * 64) * 8]);
      }
      #pragma unroll
      for (int it = 0; it < 4; ++it){
        int G = it * 256 + wv * 64 + lane;
        int row = G >> 3;
        int g = (G & 7) ^ (row & 7);
        const u16* src;
        if (kt < 8) src = Db  + (size_t)(cx * 128 + row) * COMP + kt * 64 + g * 8;
        else        src = Wte + (size_t)(cx * 128 + row) * FSZ  + (kt - 8) * 64 + g * 8;
        async16(src, &Bb[buf][(it * 256 + wv * 64) * 8]);
      }
    };

    f32x4 acc[4][4];
    #pragma unroll
    for (int i = 0; i < 4; ++i)
      #pragma unroll
      for (int j = 0; j < 4; ++j){
        f32x4 z = {0.f, 0.f, 0.f, 0.f};
        acc[i][j] = z;
      }

    stage(0, 0);
    for (int kt = 0; kt < KT; ++kt){
      const int cur = kt & 1;
      if (kt + 1 < KT){
        stage(cur ^ 1, kt + 1);
        __builtin_amdgcn_sched_barrier(0);
        asm volatile("s_waitcnt vmcnt(8)" ::: "memory");
      } else {
        __builtin_amdgcn_sched_barrier(0);
        asm volatile("s_waitcnt vmcnt(0)" ::: "memory");
      }
      MEMFENCE(); __builtin_amdgcn_s_barrier(); MEMFENCE();

      #pragma unroll
      for (int kk = 0; kk < 2; ++kk){
        s16x8 af[4], bfr[4];
        #pragma unroll
        for (int i = 0; i < 4; ++i){
          int row = wr * 64 + i * 16 + l15;
          int sg  = (kk * 4 + lq) ^ (row & 7);
          af[i] = *(const s16x8*)&Ab[cur][row * 64 + sg * 8];
        }
        #pragma unroll
        for (int j = 0; j < 4; ++j){
          int row = wc * 64 + j * 16 + l15;
          int sg  = (kk * 4 + lq) ^ (row & 7);
          bfr[j] = *(const s16x8*)&Bb[cur][row * 64 + sg * 8];
        }
        #pragma unroll
        for (int i = 0; i < 4; ++i)
          #pragma unroll
          for (int j = 0; j < 4; ++j)
            acc[i][j] = __builtin_amdgcn_mfma_f32_16x16x32_bf16(af[i], bfr[j], acc[i][j], 0, 0, 0);
      }

      MEMFENCE(); __builtin_amdgcn_s_barrier(); MEMFENCE();
    }

    // epilogue: plain f32 scatter-store (each token row written exactly once;
    // padded duplicate rows re-store identical values — benign)
    #pragma unroll
    for (int i = 0; i < 4; ++i){
      #pragma unroll
      for (int j = 0; j < 4; ++j){
        int rloc = wr * 64 + i * 16 + lq * 4;
        int col  = cx * 128 + wc * 64 + j * 16 + l15;
        #pragma unroll
        for (int r = 0; r < 4; ++r){
          int rit = rloc + r;
          out[(size_t)rowtok[rit] * OUTF + col] = acc[i][j][r];
        }
      }
    }
    __syncthreads();
  }
}

// ---------------- host launcher ----------------
extern "C" void kernel_launch(void* const* d_in, const int* in_sizes, int n_in,
                              void* d_out, int out_size, void* d_ws, size_t ws_size,
                              hipStream_t stream){
  const float* x  = (const float*)d_in[0];
  const float* sw = (const float*)d_in[1];
  const float* W  = (const float*)d_in[2];
  const float* C  = (const float*)d_in[3];
  const float* D  = (const float*)d_in[4];
  float* out = (float*)d_out;

  char* w = (char*)d_ws;
  size_t off = 0;
  auto alloc = [&](size_t bytes) -> void* {
    void* p = w + off;
    off += (bytes + 255) & ~(size_t)255;
    return p;
  };
  u16* masked = (u16*)alloc((size_t)B_TOK * INF * 2);        // 64 MiB
  u16* Acat   = (u16*)alloc((size_t)B_TOK * KCAT * 2);       // 12 MiB
  u16* Cb     = (u16*)alloc((size_t)COMP * INF * 2);         // 4 MiB
  u16* Db     = (u16*)alloc((size_t)OUTF * COMP * 2);        // 4 MiB
  u16* Wt     = (u16*)alloc((size_t)NFRAG * OUTF * FSZ * 2); // 32 MiB
  int* counts = (int*)alloc(NFRAG * CSTRIDE * sizeof(int));  // padded: 256B/expert
  int* toks   = (int*)alloc((size_t)NFRAG * B_TOK * sizeof(int));
  float* comp_f32 = (float*)alloc((size_t)B_TOK * COMP * sizeof(float)); // +16 MiB
  const bool split = (off <= ws_size);

  hipMemsetAsync(counts, 0, NFRAG * CSTRIDE * sizeof(int), stream);

  cast_bf16<<<2048, 256, 0, stream>>>(C, Cb, (COMP * INF) / 4);
  cast_bf16<<<2048, 256, 0, stream>>>(D, Db, (OUTF * COMP) / 4);
  transpose_cast_w<<<dim3(64, 4, 16), 256, 0, stream>>>(W, Wt);
  prep_kernel<<<B_TOK, 256, 0, stream>>>(x, sw, masked, Acat, counts, toks);

  if (split){
    // split-K=2: 512 blocks (2/CU, LDS-capped), atomicAdd f32 partial sums
    hipMemsetAsync(comp_f32, 0, (size_t)B_TOK * COMP * sizeof(float), stream);
    gemm_bt<4><<<dim3(COMP / 128, B_TOK / 128, 2), 256, 0, stream>>>(
        masked, INF, Cb, INF, comp_f32, COMP, 32);
    reduce_cast<<<1024, 256, 0, stream>>>(comp_f32, Acat);
  } else {
    gemm_bt<0><<<dim3(COMP / 128, B_TOK / 128, 1), 256, 0, stream>>>(
        masked, INF, Cb, INF, Acat, KCAT, 64);
  }

  // fused: out = Acat[token-gathered] @ [D^T || W_e^T]  (K=768), written once
  gemm_fused<<<dim3(OUTF / 128, 8, NFRAG), 256, 0, stream>>>(
      Acat, Db, Wt, out, counts, toks);
}

// Round 6
// 466.207 us; speedup vs baseline: 1.3066x; 1.0107x over previous
//
#include <hip/hip_runtime.h>
#include <stdint.h>

typedef unsigned short u16;
typedef __attribute__((ext_vector_type(4))) float  fvec4;
typedef __attribute__((ext_vector_type(4))) float  f32x4;
typedef __attribute__((ext_vector_type(8))) short  s16x8;
typedef __attribute__((ext_vector_type(4))) u16    u16x4;

#define AS1 __attribute__((address_space(1)))
#define AS3 __attribute__((address_space(3)))
#define MEMFENCE() asm volatile("" ::: "memory")

#define B_TOK   8192
#define NFRAG   16
#define FSZ     256
#define INF     4096
#define OUTF    4096
#define COMP    512
#define KCAT    768      // COMP + FSZ
#define CSTRIDE 64       // counts padded to 256B per expert (separate cache lines/channels)

__device__ __forceinline__ u16 f2bf(float f){
  union { float fv; unsigned int u; } v; v.fv = f;
  unsigned int u = v.u;
  u += 0x7fffu + ((u >> 16) & 1u);
  return (u16)(u >> 16);
}

__device__ __forceinline__ void async16(const void* g, void* l){
  __builtin_amdgcn_global_load_lds((const AS1 unsigned int*)g, (AS3 unsigned int*)l, 16, 0, 0);
}

// ---------------- fused cast: C and D f32 -> bf16 ----------------
__global__ void cast2_bf16(const float* __restrict__ C, const float* __restrict__ D,
                           u16* __restrict__ Cb, u16* __restrict__ Db){
  const int nq = COMP * INF / 4;          // quads per matrix (both are 2M elements)
  for (int i = blockIdx.x * blockDim.x + threadIdx.x; i < 2 * nq; i += gridDim.x * blockDim.x){
    const float* src = (i < nq) ? C : D;
    u16* dst        = (i < nq) ? Cb : Db;
    int k = (i < nq) ? i : (i - nq);
    fvec4 v = ((const fvec4*)src)[k];
    u16x4 o; o.x = f2bf(v.x); o.y = f2bf(v.y); o.z = f2bf(v.z); o.w = f2bf(v.w);
    ((u16x4*)dst)[k] = o;
  }
}

// ------------- transpose-cast expert weights: [16][256][4096] f32 -> [16][4096][256] bf16 -------------
__global__ void transpose_cast_w(const float* __restrict__ W, u16* __restrict__ Wt){
  __shared__ u16 ldsT[64][72];
  const int e  = blockIdx.z;
  const int kt = blockIdx.y;
  const int nt = blockIdx.x;
  const int t  = threadIdx.x;
  const float* Wb = W + (size_t)e * FSZ * OUTF;

  const int tr = t >> 4;
  const int tc = t & 15;
  #pragma unroll
  for (int it = 0; it < 4; ++it){
    int k = it * 16 + tr;
    fvec4 v = *(const fvec4*)(Wb + (size_t)(kt * 64 + k) * OUTF + nt * 64 + tc * 4);
    ldsT[tc*4 + 0][k] = f2bf(v.x);
    ldsT[tc*4 + 1][k] = f2bf(v.y);
    ldsT[tc*4 + 2][k] = f2bf(v.z);
    ldsT[tc*4 + 3][k] = f2bf(v.w);
  }
  __syncthreads();
  u16* Wtb = Wt + (size_t)e * OUTF * FSZ;
  const int nr = t >> 3;
  const int nc = t & 7;
  #pragma unroll
  for (int it = 0; it < 2; ++it){
    int n = it * 32 + nr;
    s16x8 val = *(const s16x8*)&ldsT[n][nc * 8];
    *(s16x8*)(Wtb + (size_t)(nt * 64 + n) * FSZ + kt * 64 + nc * 8) = val;
  }
}

// ---------------- prep: selector + argmax + bucket scatter + masked/xsel bf16 ----------------
__global__ void prep_kernel(const float* __restrict__ x, const float* __restrict__ sw,
                            u16* __restrict__ masked, u16* __restrict__ Acat,
                            int* __restrict__ counts, int* __restrict__ tok_list){
  const int b = blockIdx.x;
  const int t = threadIdx.x;
  const int w = t >> 6;                   // wave 0..3
  const int l = t & 63;                   // lane
  const float* xr = x + (size_t)b * INF;
  const fvec4* xq  = (const fvec4*)xr;
  const fvec4* swq = (const fvec4*)sw;    // [16][64] quads

  fvec4 v[4];
  float p[4];
  #pragma unroll
  for (int j = 0; j < 4; ++j){
    v[j] = xq[j * 256 + t];               // lane-contiguous 1KB per wave
    fvec4 wv = swq[(j * 4 + w) * 64 + l]; // selector weights for fragment j*4+w
    p[j] = v[j].x * wv.x + v[j].y * wv.y + v[j].z * wv.z + v[j].w * wv.w;
  }
  #pragma unroll
  for (int m = 1; m < 64; m <<= 1){
    #pragma unroll
    for (int j = 0; j < 4; ++j) p[j] += __shfl_xor(p[j], m, 64);
  }

  __shared__ float sc[NFRAG];
  if (l == 0){
    #pragma unroll
    for (int j = 0; j < 4; ++j) sc[j * 4 + w] = p[j];
  }
  __syncthreads();

  // redundant argmax on every thread (strict > from 0 == numpy first-max)
  float best = sc[0]; int sel = 0;
  #pragma unroll
  for (int i = 1; i < NFRAG; ++i){ if (sc[i] > best){ best = sc[i]; sel = i; } }

  if (t == 0){
    int pos = atomicAdd(&counts[sel * CSTRIDE], 1);
    tok_list[sel * B_TOK + pos] = b;
  }

  u16x4* mq = (u16x4*)(masked + (size_t)b * INF);
  #pragma unroll
  for (int j = 0; j < 4; ++j){
    const bool insel = ((j * 4 + w) == sel);
    u16x4 o;
    o.x = insel ? (u16)0 : f2bf(v[j].x);
    o.y = insel ? (u16)0 : f2bf(v[j].y);
    o.z = insel ? (u16)0 : f2bf(v[j].z);
    o.w = insel ? (u16)0 : f2bf(v[j].w);
    mq[j * 256 + t] = o;                  // wave-contiguous 512B
    if (insel){
      u16x4 s;
      s.x = f2bf(v[j].x); s.y = f2bf(v[j].y); s.z = f2bf(v[j].z); s.w = f2bf(v[j].w);
      ((u16x4*)(Acat + (size_t)b * KCAT + COMP))[l] = s;   // 64 lanes x 8B contiguous
    }
  }
}

// ---------------- gemm_comp: comp = masked @ Cb^T, tile 128(M)x64(N), BK=64, bf16 out into Acat ----------------
// A [8192][4096], B=Cb [512][4096], out cols [0,512) of Acat (ldc=KCAT). Grid (8, 64), 3 blocks/CU.
__global__ __launch_bounds__(256, 3)
void gemm_comp(const u16* __restrict__ A, const u16* __restrict__ B, u16* __restrict__ Cout){
  __shared__ u16 Ab[2][128 * 64];
  __shared__ u16 Bb[2][64 * 64];

  const int t    = threadIdx.x;
  const int wv   = t >> 6;
  const int lane = t & 63;
  const int cx   = blockIdx.x;            // n-tile (64 wide)
  const int ry   = blockIdx.y;            // m-tile (128 tall)
  const int l15 = lane & 15, lq = lane >> 4;
  const int KT = INF >> 6;                // 64

  auto stage = [&](int buf, int kt){
    const int k0 = kt << 6;
    #pragma unroll
    for (int it = 0; it < 4; ++it){       // A: 128 rows x 64 k
      int G = it * 256 + wv * 64 + lane;
      int row = G >> 3;
      int g = (G & 7) ^ (row & 7);
      async16(A + (size_t)(ry * 128 + row) * INF + k0 + g * 8, &Ab[buf][(it * 256 + wv * 64) * 8]);
    }
    #pragma unroll
    for (int it = 0; it < 2; ++it){       // B: 64 rows x 64 k
      int G = it * 256 + wv * 64 + lane;
      int row = G >> 3;
      int g = (G & 7) ^ (row & 7);
      async16(B + (size_t)(cx * 64 + row) * INF + k0 + g * 8, &Bb[buf][(it * 256 + wv * 64) * 8]);
    }
  };

  f32x4 acc[2][4];
  #pragma unroll
  for (int i = 0; i < 2; ++i)
    #pragma unroll
    for (int j = 0; j < 4; ++j){
      f32x4 z = {0.f, 0.f, 0.f, 0.f};
      acc[i][j] = z;
    }

  stage(0, 0);
  for (int kt = 0; kt < KT; ++kt){
    const int cur = kt & 1;
    if (kt + 1 < KT){
      stage(cur ^ 1, kt + 1);
      __builtin_amdgcn_sched_barrier(0);
      asm volatile("s_waitcnt vmcnt(6)" ::: "memory");
    } else {
      __builtin_amdgcn_sched_barrier(0);
      asm volatile("s_waitcnt vmcnt(0)" ::: "memory");
    }
    MEMFENCE(); __builtin_amdgcn_s_barrier(); MEMFENCE();

    #pragma unroll
    for (int kk = 0; kk < 2; ++kk){
      s16x8 af[2], bfr[4];
      #pragma unroll
      for (int i = 0; i < 2; ++i){        // wave wv owns rows [wv*32, wv*32+32)
        int row = wv * 32 + i * 16 + l15;
        int sg  = (kk * 4 + lq) ^ (row & 7);
        af[i] = *(const s16x8*)&Ab[cur][row * 64 + sg * 8];
      }
      #pragma unroll
      for (int j = 0; j < 4; ++j){
        int row = j * 16 + l15;
        int sg  = (kk * 4 + lq) ^ (row & 7);
        bfr[j] = *(const s16x8*)&Bb[cur][row * 64 + sg * 8];
      }
      #pragma unroll
      for (int i = 0; i < 2; ++i)
        #pragma unroll
        for (int j = 0; j < 4; ++j)
          acc[i][j] = __builtin_amdgcn_mfma_f32_16x16x32_bf16(af[i], bfr[j], acc[i][j], 0, 0, 0);
    }

    MEMFENCE(); __builtin_amdgcn_s_barrier(); MEMFENCE();
  }

  // epilogue: bf16 into Acat cols [0,512), ldc = KCAT
  #pragma unroll
  for (int i = 0; i < 2; ++i){
    #pragma unroll
    for (int j = 0; j < 4; ++j){
      int rloc = wv * 32 + i * 16 + lq * 4;
      int col  = cx * 64 + j * 16 + l15;
      #pragma unroll
      for (int r = 0; r < 4; ++r){
        Cout[(size_t)(ry * 128 + rloc + r) * KCAT + col] = f2bf(acc[i][j][r]);
      }
    }
  }
}

// ---------------- fused grouped GEMM: out = Acat[gathered] @ [D^T || W_e^T], K=768 ----------------
__global__ __launch_bounds__(256, 2)
void gemm_fused(const u16* __restrict__ Acat, const u16* __restrict__ Db,
                const u16* __restrict__ Wt, float* __restrict__ out,
                const int* __restrict__ counts, const int* __restrict__ tok_list){
  __shared__ u16 Ab[2][128 * 64];
  __shared__ u16 Bb[2][128 * 64];
  __shared__ int rowtok[128];

  const int t    = threadIdx.x;
  const int wv   = t >> 6;
  const int lane = t & 63;
  const int cx   = blockIdx.x;
  const int e    = blockIdx.z;
  const int Me   = counts[e * CSTRIDE];
  const u16* Wte = Wt + (size_t)e * OUTF * FSZ;
  const int KT   = KCAT >> 6;   // 12
  const int wr = wv >> 1, wc = wv & 1;
  const int l15 = lane & 15, lq = lane >> 4;

  for (int ry = blockIdx.y; ry * 128 < Me; ry += (int)gridDim.y){
    if (t < 128){
      int r  = ry * 128 + t;
      int rc = (r < Me) ? r : (Me - 1);
      rowtok[t] = tok_list[e * B_TOK + rc];
    }
    __syncthreads();

    auto stage = [&](int buf, int kt){
      #pragma unroll
      for (int it = 0; it < 4; ++it){
        int G = it * 256 + wv * 64 + lane;
        int row = G >> 3;
        int g = (G & 7) ^ (row & 7);
        async16(Acat + (size_t)rowtok[row] * KCAT + kt * 64 + g * 8, &Ab[buf][(it * 256 + wv * 64) * 8]);
      }
      #pragma unroll
      for (int it = 0; it < 4; ++it){
        int G = it * 256 + wv * 64 + lane;
        int row = G >> 3;
        int g = (G & 7) ^ (row & 7);
        const u16* src;
        if (kt < 8) src = Db  + (size_t)(cx * 128 + row) * COMP + kt * 64 + g * 8;
        else        src = Wte + (size_t)(cx * 128 + row) * FSZ  + (kt - 8) * 64 + g * 8;
        async16(src, &Bb[buf][(it * 256 + wv * 64) * 8]);
      }
    };

    f32x4 acc[4][4];
    #pragma unroll
    for (int i = 0; i < 4; ++i)
      #pragma unroll
      for (int j = 0; j < 4; ++j){
        f32x4 z = {0.f, 0.f, 0.f, 0.f};
        acc[i][j] = z;
      }

    stage(0, 0);
    for (int kt = 0; kt < KT; ++kt){
      const int cur = kt & 1;
      if (kt + 1 < KT){
        stage(cur ^ 1, kt + 1);
        __builtin_amdgcn_sched_barrier(0);
        asm volatile("s_waitcnt vmcnt(8)" ::: "memory");
      } else {
        __builtin_amdgcn_sched_barrier(0);
        asm volatile("s_waitcnt vmcnt(0)" ::: "memory");
      }
      MEMFENCE(); __builtin_amdgcn_s_barrier(); MEMFENCE();

      #pragma unroll
      for (int kk = 0; kk < 2; ++kk){
        s16x8 af[4], bfr[4];
        #pragma unroll
        for (int i = 0; i < 4; ++i){
          int row = wr * 64 + i * 16 + l15;
          int sg  = (kk * 4 + lq) ^ (row & 7);
          af[i] = *(const s16x8*)&Ab[cur][row * 64 + sg * 8];
        }
        #pragma unroll
        for (int j = 0; j < 4; ++j){
          int row = wc * 64 + j * 16 + l15;
          int sg  = (kk * 4 + lq) ^ (row & 7);
          bfr[j] = *(const s16x8*)&Bb[cur][row * 64 + sg * 8];
        }
        #pragma unroll
        for (int i = 0; i < 4; ++i)
          #pragma unroll
          for (int j = 0; j < 4; ++j)
            acc[i][j] = __builtin_amdgcn_mfma_f32_16x16x32_bf16(af[i], bfr[j], acc[i][j], 0, 0, 0);
      }

      MEMFENCE(); __builtin_amdgcn_s_barrier(); MEMFENCE();
    }

    // epilogue: plain f32 scatter-store (each token row written exactly once)
    #pragma unroll
    for (int i = 0; i < 4; ++i){
      #pragma unroll
      for (int j = 0; j < 4; ++j){
        int rloc = wr * 64 + i * 16 + lq * 4;
        int col  = cx * 128 + wc * 64 + j * 16 + l15;
        #pragma unroll
        for (int r = 0; r < 4; ++r){
          int rit = rloc + r;
          out[(size_t)rowtok[rit] * OUTF + col] = acc[i][j][r];
        }
      }
    }
    __syncthreads();
  }
}

// ---------------- host launcher ----------------
extern "C" void kernel_launch(void* const* d_in, const int* in_sizes, int n_in,
                              void* d_out, int out_size, void* d_ws, size_t ws_size,
                              hipStream_t stream){
  const float* x  = (const float*)d_in[0];
  const float* sw = (const float*)d_in[1];
  const float* W  = (const float*)d_in[2];
  const float* C  = (const float*)d_in[3];
  const float* D  = (const float*)d_in[4];
  float* out = (float*)d_out;

  char* w = (char*)d_ws;
  size_t off = 0;
  auto alloc = [&](size_t bytes) -> void* {
    void* p = w + off;
    off += (bytes + 255) & ~(size_t)255;
    return p;
  };
  u16* masked = (u16*)alloc((size_t)B_TOK * INF * 2);        // 64 MiB
  u16* Acat   = (u16*)alloc((size_t)B_TOK * KCAT * 2);       // 12 MiB
  u16* Cb     = (u16*)alloc((size_t)COMP * INF * 2);         // 4 MiB
  u16* Db     = (u16*)alloc((size_t)OUTF * COMP * 2);        // 4 MiB
  u16* Wt     = (u16*)alloc((size_t)NFRAG * OUTF * FSZ * 2); // 32 MiB
  int* counts = (int*)alloc(NFRAG * CSTRIDE * sizeof(int));  // padded: 256B/expert
  int* toks   = (int*)alloc((size_t)NFRAG * B_TOK * sizeof(int));

  hipMemsetAsync(counts, 0, NFRAG * CSTRIDE * sizeof(int), stream);

  cast2_bf16<<<2048, 256, 0, stream>>>(C, D, Cb, Db);
  transpose_cast_w<<<dim3(64, 4, 16), 256, 0, stream>>>(W, Wt);
  prep_kernel<<<B_TOK, 256, 0, stream>>>(x, sw, masked, Acat, counts, toks);

  // compressed = masked @ C^T -> bf16 into Acat cols [0,512); 512 blocks, 3/CU
  gemm_comp<<<dim3(COMP / 64, B_TOK / 128), 256, 0, stream>>>(masked, Cb, Acat);

  // fused: out = Acat[token-gathered] @ [D^T || W_e^T]  (K=768), written once
  gemm_fused<<<dim3(OUTF / 128, 4, NFRAG), 256, 0, stream>>>(
      Acat, Db, Wt, out, counts, toks);
}